// Round 1
// baseline (284.188 us; speedup 1.0000x reference)
//
#include <hip/hip_runtime.h>
#include <math.h>

#define N_NODES 20000
#define N_EDGES 160000
#define EPSB 1e-5f
#define SLOPE 0.01f

// ---- workspace layout (float element offsets) ----
#define OFF_DEG    0        // int[20000]
#define OFF_DINV   20000    // float[20000]
#define OFF_AGG1   40000    // float[20000]
#define OFF_AGG2   60000    // float[20000]
#define OFF_CNODE  80000    // float[20000]
#define OFF_V      100000   // float[1024]
#define OFF_U      101024   // float[1024]
#define OFF_R      102048   // float[256]
#define OFF_RU     102304   // float[256]
#define OFF_S      102560   // float[256]
#define OFF_WPAD   102816   // float[256*128]  (lW2 padded 124->128 cols)
#define OFF_LB2P   135584   // float[128]
#define OFF_RRS    135712   // float4[256]  (16B aligned: 135712*4 % 16 == 0)

__global__ void k_deg(const int* __restrict__ dst, int* __restrict__ deg) {
    int e = blockIdx.x * blockDim.x + threadIdx.x;
    if (e < N_EDGES) atomicAdd(&deg[dst[e]], 1);
}

__global__ void k_dinv(const int* __restrict__ deg, float* __restrict__ dinv) {
    int i = blockIdx.x * blockDim.x + threadIdx.x;
    if (i < N_NODES) dinv[i] = rsqrtf((float)(deg[i] + 1));  // +1 = self loop
}

// self-loop init for agg1 and cnode
__global__ void k_agg_init2(const float* __restrict__ dinv, const float* __restrict__ x,
                            float* __restrict__ agg1, float* __restrict__ cnode) {
    int i = blockIdx.x * blockDim.x + threadIdx.x;
    if (i < N_NODES) {
        float di = dinv[i];
        float d2 = di * di;
        agg1[i]  = d2 * x[i];
        cnode[i] = d2;
    }
}

__global__ void k_agg_edges2(const int* __restrict__ src, const int* __restrict__ dst,
                             const float* __restrict__ dinv, const float* __restrict__ x,
                             float* __restrict__ agg1, float* __restrict__ cnode) {
    int e = blockIdx.x * blockDim.x + threadIdx.x;
    if (e < N_EDGES) {
        int s = src[e], d = dst[e];
        float nrm = dinv[s] * dinv[d];
        atomicAdd(&agg1[d], nrm * x[s]);
        atomicAdd(&cnode[d], nrm);
    }
}

__global__ void k_agg_init(const float* __restrict__ dinv, const float* __restrict__ f,
                           float* __restrict__ out) {
    int i = blockIdx.x * blockDim.x + threadIdx.x;
    if (i < N_NODES) out[i] = dinv[i] * dinv[i] * f[i];
}

__global__ void k_agg_edges(const int* __restrict__ src, const int* __restrict__ dst,
                            const float* __restrict__ dinv, const float* __restrict__ f,
                            float* __restrict__ out) {
    int e = blockIdx.x * blockDim.x + threadIdx.x;
    if (e < N_EDGES) {
        int s = src[e], d = dst[e];
        atomicAdd(&out[d], dinv[s] * dinv[d] * f[s]);
    }
}

// v[k] = sum_c W1[c]*W2[c,k];  u[k] = sum_c b1[c]*W2[c,k]
__global__ void k_v(const float* __restrict__ W1, const float* __restrict__ b1,
                    const float* __restrict__ W2, float* __restrict__ v, float* __restrict__ u) {
    int k  = blockIdx.x * 128 + threadIdx.x;   // 0..1023
    int c0 = blockIdx.y * 128;
    float av = 0.f, au = 0.f;
    for (int c = c0; c < c0 + 128; ++c) {
        float w = W2[c * 1024 + k];
        av = fmaf(W1[c], w, av);
        au = fmaf(b1[c], w, au);
    }
    atomicAdd(&v[k], av);
    atomicAdd(&u[k], au);
}

// fold BN into p,q; then r = p@lW1, ru = pu@lW1, s = q@lW1 + lb1
__global__ void k_rs(const float* __restrict__ v, const float* __restrict__ u,
                     const float* __restrict__ gamma, const float* __restrict__ beta,
                     const float* __restrict__ mean, const float* __restrict__ var,
                     const float* __restrict__ b2, const float* __restrict__ lW1,
                     const float* __restrict__ lb1,
                     float* __restrict__ r, float* __restrict__ ru, float* __restrict__ s) {
    int m  = threadIdx.x;          // 0..255
    int k0 = blockIdx.y * 64;
    float ar = 0.f, aru = 0.f, as = 0.f;
    for (int k = k0; k < k0 + 64; ++k) {
        float g = gamma[k] * rsqrtf(var[k] + EPSB);
        float w = lW1[k * 256 + m];
        ar  = fmaf(v[k] * g, w, ar);
        aru = fmaf(u[k] * g, w, aru);
        as  = fmaf(fmaf(b2[k] - mean[k], g, beta[k]), w, as);
    }
    if (blockIdx.y == 0) as += lb1[m];
    atomicAdd(&r[m], ar);
    atomicAdd(&ru[m], aru);
    atomicAdd(&s[m], as);
}

__global__ void k_pad(const float* __restrict__ lW2, const float* __restrict__ lb2,
                      const float* __restrict__ r, const float* __restrict__ ru,
                      const float* __restrict__ s,
                      float* __restrict__ wpad, float* __restrict__ lb2p,
                      float4* __restrict__ rrs) {
    int i = blockIdx.x * blockDim.x + threadIdx.x;
    if (i < 256 * 128) {
        int m = i >> 7, j = i & 127;
        wpad[i] = (j < 124) ? lW2[m * 124 + j] : 0.f;
    }
    if (i < 128) lb2p[i] = (i < 124) ? lb2[i] : -1e30f;
    if (i < 256) rrs[i] = make_float4(r[i], ru[i], s[i], 0.f);
}

// Final stage: per node  t[m] = leaky(agg2*r[m] + cnode*ru[m] + s[m]);
// logits = t @ lW2 + lb2; out = log_softmax(logits).
// Block = 256 thr = 4 waves; block handles 64 nodes (node = lane).
// Wave w handles m-chunk [64w, 64w+64); lW2 addresses are wave-uniform -> scalar loads.
__global__ __launch_bounds__(256) void k_final(
    const float* __restrict__ agg2, const float* __restrict__ cnode,
    const float4* __restrict__ rrs, const float* __restrict__ wpad,
    const float* __restrict__ lb2p, float* __restrict__ out) {
    __shared__ float red[64 * 129];   // stride 129: bank = (lane + j) % 32, conflict-free
    int tid  = threadIdx.x;
    int lane = tid & 63;
    int wave = __builtin_amdgcn_readfirstlane(tid >> 6);  // provably wave-uniform
    int node = blockIdx.x * 64 + lane;
    bool valid = node < N_NODES;
    float a  = valid ? agg2[node]  : 0.f;
    float cn = valid ? cnode[node] : 0.f;

    float acc[128];
#pragma unroll
    for (int j = 0; j < 128; ++j) acc[j] = 0.f;

    const int m0 = wave * 64;
    for (int mi = 0; mi < 64; ++mi) {
        int m = m0 + mi;
        float4 c = rrs[m];                                  // uniform -> s_load
        float t = fmaf(cn, c.y, fmaf(a, c.x, c.z));
        t = fmaf(SLOPE, fminf(t, 0.f), fmaxf(t, 0.f));      // leaky relu
        const float4* wrow = (const float4*)(wpad + (m << 7));  // uniform
#pragma unroll
        for (int q = 0; q < 32; ++q) {
            float4 w = wrow[q];
            acc[4 * q + 0] = fmaf(t, w.x, acc[4 * q + 0]);
            acc[4 * q + 1] = fmaf(t, w.y, acc[4 * q + 1]);
            acc[4 * q + 2] = fmaf(t, w.z, acc[4 * q + 2]);
            acc[4 * q + 3] = fmaf(t, w.w, acc[4 * q + 3]);
        }
    }

    // init reduction buffer with lb2 (pad cols = -1e30 so they never win max, exp->0)
    {
        int row = tid >> 2, jq = (tid & 3) << 5;
        for (int j = 0; j < 32; ++j) red[row * 129 + jq + j] = lb2p[jq + j];
    }
    __syncthreads();
#pragma unroll
    for (int j = 0; j < 128; ++j) atomicAdd(&red[lane * 129 + j], acc[j]);
    __syncthreads();

    // log_softmax: 4 lanes per row
    int row = tid >> 2, jq = (tid & 3) << 5;
    const float* rrow = &red[row * 129 + jq];
    float mx = -1e30f;
    for (int j = 0; j < 32; ++j) mx = fmaxf(mx, rrow[j]);
    mx = fmaxf(mx, __shfl_xor(mx, 1, 4));
    mx = fmaxf(mx, __shfl_xor(mx, 2, 4));
    float sm = 0.f;
    for (int j = 0; j < 32; ++j) sm += expf(rrow[j] - mx);
    sm += __shfl_xor(sm, 1, 4);
    sm += __shfl_xor(sm, 2, 4);
    float lz = mx + logf(sm);
    int onode = blockIdx.x * 64 + row;
    if (onode < N_NODES) {
        int jend = 124 - jq; if (jend > 32) jend = 32;
        for (int j = 0; j < jend; ++j) out[onode * 124 + jq + j] = rrow[j] - lz;
    }
}

extern "C" void kernel_launch(void* const* d_in, const int* in_sizes, int n_in,
                              void* d_out, int out_size, void* d_ws, size_t ws_size,
                              hipStream_t stream) {
    const float* x     = (const float*)d_in[0];
    const int*   ei    = (const int*)d_in[1];
    const int*   src   = ei;
    const int*   dst   = ei + N_EDGES;
    const float* W1    = (const float*)d_in[2];
    const float* b1    = (const float*)d_in[3];
    const float* W2    = (const float*)d_in[4];
    const float* b2    = (const float*)d_in[5];
    const float* gamma = (const float*)d_in[6];
    const float* beta  = (const float*)d_in[7];
    const float* rmean = (const float*)d_in[8];
    const float* rvar  = (const float*)d_in[9];
    const float* lW1   = (const float*)d_in[10];
    const float* lb1   = (const float*)d_in[11];
    const float* lW2   = (const float*)d_in[12];
    const float* lb2   = (const float*)d_in[13];
    float* out = (float*)d_out;
    float* ws  = (float*)d_ws;

    int*   deg   = (int*)(ws + OFF_DEG);
    float* dinv  = ws + OFF_DINV;
    float* agg1  = ws + OFF_AGG1;
    float* agg2  = ws + OFF_AGG2;
    float* cnode = ws + OFF_CNODE;
    float* v     = ws + OFF_V;
    float* u     = ws + OFF_U;
    float* r     = ws + OFF_R;
    float* ru    = ws + OFF_RU;
    float* s     = ws + OFF_S;
    float* wpad  = ws + OFF_WPAD;
    float* lb2p  = ws + OFF_LB2P;
    float4* rrs  = (float4*)(ws + OFF_RRS);

    // zero: deg, and v/u/r/ru/s (atomic accumulation targets)
    hipMemsetAsync(deg, 0, N_NODES * sizeof(int), stream);
    hipMemsetAsync(v, 0, (1024 + 1024 + 256 + 256 + 256) * sizeof(float), stream);

    k_deg<<<(N_EDGES + 255) / 256, 256, 0, stream>>>(dst, deg);
    k_v<<<dim3(8, 16), 128, 0, stream>>>(W1, b1, W2, v, u);
    k_dinv<<<(N_NODES + 255) / 256, 256, 0, stream>>>(deg, dinv);
    k_agg_init2<<<(N_NODES + 255) / 256, 256, 0, stream>>>(dinv, x, agg1, cnode);
    k_agg_edges2<<<(N_EDGES + 255) / 256, 256, 0, stream>>>(src, dst, dinv, x, agg1, cnode);
    k_agg_init<<<(N_NODES + 255) / 256, 256, 0, stream>>>(dinv, agg1, agg2);
    k_agg_edges<<<(N_EDGES + 255) / 256, 256, 0, stream>>>(src, dst, dinv, agg1, agg2);
    k_rs<<<dim3(1, 16), 256, 0, stream>>>(v, u, gamma, beta, rmean, rvar, b2, lW1, lb1, r, ru, s);
    k_pad<<<128, 256, 0, stream>>>(lW2, lb2, r, ru, s, wpad, lb2p, rrs);
    k_final<<<(N_NODES + 63) / 64, 256, 0, stream>>>(agg2, cnode, rrs, wpad, lb2p, out);
}

// Round 2
// 204.075 us; speedup vs baseline: 1.3926x; 1.3926x over previous
//
#include <hip/hip_runtime.h>
#include <math.h>

#define N_NODES 20000
#define N_EDGES 160000
#define EPSB 1e-5f
#define SLOPE 0.01f

// ---- workspace layout (float element offsets) ----
#define OFF_DEG    0        // int[20000]
#define OFF_DINV   20000    // float[20000]
#define OFF_AGG1   40000    // float[20000]
#define OFF_AGG2   60000    // float[20000]
#define OFF_CNODE  80000    // float[20000]
#define OFF_V      100000   // float[1024]
#define OFF_U      101024   // float[1024]
#define OFF_R      102048   // float[256]
#define OFF_RU     102304   // float[256]
#define OFF_S      102560   // float[256]
#define OFF_ZEND   102816   // end of zeroed region
#define OFF_WPAD   102816   // float[256*128]  (lW2 padded 124->128 cols)
#define OFF_LB2P   135584   // float[128]
#define OFF_RRS    135712   // float4[256]  (16B aligned: 135712*4 % 16 == 0)

__global__ void k_deg(const int* __restrict__ dst, int* __restrict__ deg) {
    int e = blockIdx.x * blockDim.x + threadIdx.x;
    if (e < N_EDGES) atomicAdd(&deg[dst[e]], 1);
}

// dinv + self-loop init for agg1 and cnode (merged k_dinv + k_agg_init2)
__global__ void k_prep(const int* __restrict__ deg, const float* __restrict__ x,
                       float* __restrict__ dinv, float* __restrict__ agg1,
                       float* __restrict__ cnode) {
    int i = blockIdx.x * blockDim.x + threadIdx.x;
    if (i < N_NODES) {
        float di = rsqrtf((float)(deg[i] + 1));  // +1 = self loop
        dinv[i] = di;
        float d2 = di * di;
        agg1[i]  = d2 * x[i];
        cnode[i] = d2;
    }
}

__global__ void k_agg_edges2(const int* __restrict__ src, const int* __restrict__ dst,
                             const float* __restrict__ dinv, const float* __restrict__ x,
                             float* __restrict__ agg1, float* __restrict__ cnode) {
    int e = blockIdx.x * blockDim.x + threadIdx.x;
    if (e < N_EDGES) {
        int s = src[e], d = dst[e];
        float nrm = dinv[s] * dinv[d];
        atomicAdd(&agg1[d], nrm * x[s]);
        atomicAdd(&cnode[d], nrm);
    }
}

__global__ void k_agg_init(const float* __restrict__ dinv, const float* __restrict__ f,
                           float* __restrict__ out) {
    int i = blockIdx.x * blockDim.x + threadIdx.x;
    if (i < N_NODES) out[i] = dinv[i] * dinv[i] * f[i];
}

__global__ void k_agg_edges(const int* __restrict__ src, const int* __restrict__ dst,
                            const float* __restrict__ dinv, const float* __restrict__ f,
                            float* __restrict__ out) {
    int e = blockIdx.x * blockDim.x + threadIdx.x;
    if (e < N_EDGES) {
        int s = src[e], d = dst[e];
        atomicAdd(&out[d], dinv[s] * dinv[d] * f[s]);
    }
}

// v[k] = sum_c W1[c]*W2[c,k];  u[k] = sum_c b1[c]*W2[c,k]
__global__ void k_v(const float* __restrict__ W1, const float* __restrict__ b1,
                    const float* __restrict__ W2, float* __restrict__ v, float* __restrict__ u) {
    int k  = blockIdx.x * 256 + threadIdx.x;   // 0..1023
    int c0 = blockIdx.y * 128;
    float av = 0.f, au = 0.f;
    for (int c = c0; c < c0 + 128; ++c) {
        float w = W2[c * 1024 + k];
        av = fmaf(W1[c], w, av);
        au = fmaf(b1[c], w, au);
    }
    atomicAdd(&v[k], av);
    atomicAdd(&u[k], au);
}

// fold BN into p,q; then r = p@lW1, ru = pu@lW1, s = q@lW1 + lb1
__global__ void k_rs(const float* __restrict__ v, const float* __restrict__ u,
                     const float* __restrict__ gamma, const float* __restrict__ beta,
                     const float* __restrict__ mean, const float* __restrict__ var,
                     const float* __restrict__ b2, const float* __restrict__ lW1,
                     const float* __restrict__ lb1,
                     float* __restrict__ r, float* __restrict__ ru, float* __restrict__ s) {
    int m  = threadIdx.x;          // 0..255
    int k0 = blockIdx.y * 64;
    float ar = 0.f, aru = 0.f, as = 0.f;
    for (int k = k0; k < k0 + 64; ++k) {
        float g = gamma[k] * rsqrtf(var[k] + EPSB);
        float w = lW1[k * 256 + m];
        ar  = fmaf(v[k] * g, w, ar);
        aru = fmaf(u[k] * g, w, aru);
        as  = fmaf(fmaf(b2[k] - mean[k], g, beta[k]), w, as);
    }
    if (blockIdx.y == 0) as += lb1[m];
    atomicAdd(&r[m], ar);
    atomicAdd(&ru[m], aru);
    atomicAdd(&s[m], as);
}

__global__ void k_pad(const float* __restrict__ lW2, const float* __restrict__ lb2,
                      const float* __restrict__ r, const float* __restrict__ ru,
                      const float* __restrict__ s,
                      float* __restrict__ wpad, float* __restrict__ lb2p,
                      float4* __restrict__ rrs) {
    int i = blockIdx.x * blockDim.x + threadIdx.x;
    if (i < 256 * 128) {
        int m = i >> 7, j = i & 127;
        wpad[i] = (j < 124) ? lW2[m * 124 + j] : 0.f;
    }
    if (i < 128) lb2p[i] = (i < 124) ? lb2[i] : -1e30f;
    if (i < 256) rrs[i] = make_float4(r[i], ru[i], s[i], 0.f);
}

// Final stage: per node  t[m] = leaky(agg2*r[m] + cnode*ru[m] + s[m]);
// logits = t @ lW2 + lb2; out = log_softmax(logits).
// Block = 256 thr = 4 waves; block handles 64 nodes.
// Thread owns (node = lane, 32-col j-chunk = wave): acc[32] stays in VGPRs
// (round-1 acc[128] spilled: VGPR_Count=84 < 128 needed -> scratch RMW storm).
// Weight addresses are wave-uniform (readfirstlane'd wave id) -> broadcast loads
// from L2-hot 128 KB wpad. No LDS atomics: each thread owns distinct red slots.
#define RSTRIDE 133   // odd stride: 64 lanes x stride-133 scalar stores = 2-way bank alias (free)
__global__ __launch_bounds__(256) void k_final(
    const float* __restrict__ agg2, const float* __restrict__ cnode,
    const float4* __restrict__ rrs, const float4* __restrict__ wpad4,
    const float* __restrict__ lb2p, float* __restrict__ out) {
    __shared__ float red[64 * RSTRIDE];   // 34 KB -> 4 blocks/CU
    int tid  = threadIdx.x;
    int lane = tid & 63;
    int wave = __builtin_amdgcn_readfirstlane(tid >> 6);  // j-chunk, provably uniform
    int node = blockIdx.x * 64 + lane;
    bool valid = node < N_NODES;
    float a  = valid ? agg2[node]  : 0.f;
    float cn = valid ? cnode[node] : 0.f;

    float acc[32];
#pragma unroll
    for (int j = 0; j < 32; ++j) acc[j] = 0.f;

    const int jq4 = wave * 8;   // float4 offset of this wave's 32-col chunk
#pragma unroll 4
    for (int m = 0; m < 256; ++m) {
        float4 c = rrs[m];                                  // uniform address
        float t = fmaf(cn, c.y, fmaf(a, c.x, c.z));
        t = fmaf(SLOPE, fminf(t, 0.f), fmaxf(t, 0.f));      // leaky relu
        const float4* wrow = wpad4 + m * 32 + jq4;          // uniform address
#pragma unroll
        for (int q = 0; q < 8; ++q) {
            float4 w = wrow[q];
            acc[4 * q + 0] = fmaf(t, w.x, acc[4 * q + 0]);
            acc[4 * q + 1] = fmaf(t, w.y, acc[4 * q + 1]);
            acc[4 * q + 2] = fmaf(t, w.z, acc[4 * q + 2]);
            acc[4 * q + 3] = fmaf(t, w.w, acc[4 * q + 3]);
        }
    }

    // non-atomic reduction write: thread owns cols [32*wave, 32*wave+32) of its node
    const int col0 = wave * 32;
#pragma unroll
    for (int j = 0; j < 32; ++j)
        red[lane * RSTRIDE + col0 + j] = acc[j] + lb2p[col0 + j];  // pad cols: 0 + (-1e30)
    __syncthreads();

    // log_softmax: 4 lanes per row
    int row = tid >> 2, jq = (tid & 3) << 5;
    const float* rrow = &red[row * RSTRIDE + jq];
    float mx = -1e30f;
#pragma unroll
    for (int j = 0; j < 32; ++j) mx = fmaxf(mx, rrow[j]);
    mx = fmaxf(mx, __shfl_xor(mx, 1, 4));
    mx = fmaxf(mx, __shfl_xor(mx, 2, 4));
    float sm = 0.f;
#pragma unroll
    for (int j = 0; j < 32; ++j) sm += expf(rrow[j] - mx);
    sm += __shfl_xor(sm, 1, 4);
    sm += __shfl_xor(sm, 2, 4);
    float lz = mx + logf(sm);
    int onode = blockIdx.x * 64 + row;
    if (onode < N_NODES) {
        int jend = 124 - jq; if (jend > 32) jend = 32;
        for (int j = 0; j < jend; ++j) out[onode * 124 + jq + j] = rrow[j] - lz;
    }
}

extern "C" void kernel_launch(void* const* d_in, const int* in_sizes, int n_in,
                              void* d_out, int out_size, void* d_ws, size_t ws_size,
                              hipStream_t stream) {
    const float* x     = (const float*)d_in[0];
    const int*   ei    = (const int*)d_in[1];
    const int*   src   = ei;
    const int*   dst   = ei + N_EDGES;
    const float* W1    = (const float*)d_in[2];
    const float* b1    = (const float*)d_in[3];
    const float* W2    = (const float*)d_in[4];
    const float* b2    = (const float*)d_in[5];
    const float* gamma = (const float*)d_in[6];
    const float* beta  = (const float*)d_in[7];
    const float* rmean = (const float*)d_in[8];
    const float* rvar  = (const float*)d_in[9];
    const float* lW1   = (const float*)d_in[10];
    const float* lb1   = (const float*)d_in[11];
    const float* lW2   = (const float*)d_in[12];
    const float* lb2   = (const float*)d_in[13];
    float* out = (float*)d_out;
    float* ws  = (float*)d_ws;

    int*   deg   = (int*)(ws + OFF_DEG);
    float* dinv  = ws + OFF_DINV;
    float* agg1  = ws + OFF_AGG1;
    float* agg2  = ws + OFF_AGG2;
    float* cnode = ws + OFF_CNODE;
    float* v     = ws + OFF_V;
    float* u     = ws + OFF_U;
    float* r     = ws + OFF_R;
    float* ru    = ws + OFF_RU;
    float* s     = ws + OFF_S;
    float* wpad  = ws + OFF_WPAD;
    float* lb2p  = ws + OFF_LB2P;
    float4* rrs  = (float4*)(ws + OFF_RRS);

    // single memset covers deg + all atomic-accumulation targets (and scratch in between)
    hipMemsetAsync(ws, 0, OFF_ZEND * sizeof(float), stream);

    k_deg<<<(N_EDGES + 255) / 256, 256, 0, stream>>>(dst, deg);
    k_v<<<dim3(4, 16), 256, 0, stream>>>(W1, b1, W2, v, u);
    k_prep<<<(N_NODES + 255) / 256, 256, 0, stream>>>(deg, x, dinv, agg1, cnode);
    k_agg_edges2<<<(N_EDGES + 255) / 256, 256, 0, stream>>>(src, dst, dinv, x, agg1, cnode);
    k_agg_init<<<(N_NODES + 255) / 256, 256, 0, stream>>>(dinv, agg1, agg2);
    k_agg_edges<<<(N_EDGES + 255) / 256, 256, 0, stream>>>(src, dst, dinv, agg1, agg2);
    k_rs<<<dim3(1, 16), 256, 0, stream>>>(v, u, gamma, beta, rmean, rvar, b2, lW1, lb1, r, ru, s);
    k_pad<<<128, 256, 0, stream>>>(lW2, lb2, r, ru, s, wpad, lb2p, rrs);
    k_final<<<(N_NODES + 63) / 64, 256, 0, stream>>>(agg2, cnode, rrs, (const float4*)wpad, lb2p, out);
}